// Round 9
// baseline (402.250 us; speedup 1.0000x reference)
//
#include <hip/hip_runtime.h>
#include <math.h>

#define HEADS 8
#define DOUT 64
#define DIN 256
#define HC 512  /* HEADS*DOUT */
#define NEG_SLOPE 0.2f

typedef __bf16 bf16;
typedef __bf16 bf16x8 __attribute__((ext_vector_type(8)));
typedef float f32x4 __attribute__((ext_vector_type(4)));

__device__ __forceinline__ float lrelu(float v) { return v > 0.f ? v : NEG_SLOPE * v; }
__device__ __forceinline__ float bflo(unsigned u) { return __uint_as_float(u << 16); }
__device__ __forceinline__ float bfhi(unsigned u) { return __uint_as_float(u & 0xffff0000u); }

// acc[0..3] weighted by w0 (head 2hp), acc[4..7] by w1 (head 2hp+1)
__device__ __forceinline__ void fma8x2(float* acc, uint4 u, float w0, float w1) {
    acc[0] += w0 * bflo(u.x); acc[1] += w0 * bfhi(u.x);
    acc[2] += w0 * bflo(u.y); acc[3] += w0 * bfhi(u.y);
    acc[4] += w1 * bflo(u.z); acc[5] += w1 * bfhi(u.z);
    acc[6] += w1 * bflo(u.w); acc[7] += w1 * bfhi(u.w);
}

// ---------------------------------------------------------------------------
// W prep: Wt[h][c][k] = bf16(W[h][k][c]); block 0 also zeroes the 256-int
// work-claim counter array used by agg (stream-ordered, runs first).
// ---------------------------------------------------------------------------
__global__ void wprep_kernel(const float* __restrict__ W, bf16* __restrict__ Wt,
                             int* __restrict__ cnt) {
    if (blockIdx.x == 0) cnt[threadIdx.x] = 0;
    int idx = blockIdx.x * 256 + threadIdx.x;
    int h = idx >> 14, rem = idx & 16383, k = rem >> 6, c = rem & 63;
    Wt[(((size_t)h * 64 + c) << 8) + k] = (bf16)W[idx];
}

// ---------------------------------------------------------------------------
// MFMA GEMM + fused logits — round-0 proven kernel (fp32 x staging,
// 128x128 tile, stride-40 LDS). xpb stored SWIZZLED:
//   elem index = row*512 + hp*128 + l16*8 + c,  actual col = hp*128 + c*16 + l16
// ---------------------------------------------------------------------------
__global__ __launch_bounds__(256) void gemm_kernel(const float* __restrict__ x,
                                                   const bf16* __restrict__ Wt,
                                                   bf16* __restrict__ xpb,
                                                   const float* __restrict__ a_src,
                                                   const float* __restrict__ a_dst,
                                                   float* __restrict__ als,
                                                   float* __restrict__ ald, int N) {
    __shared__ bf16 Alds[128 * 40];
    __shared__ bf16 Blds[128 * 40];

    int m0 = blockIdx.x * 128;
    int colbase = blockIdx.y * 128;  // heads 2y, 2y+1

    int t = threadIdx.x;
    int wv = t >> 6, lane = t & 63, quad = lane >> 4, l16 = lane & 15;
    int k8 = quad * 8;

    f32x4 acc[2][8] = {};

    for (int kt = 0; kt < DIN; kt += 32) {
        {
            int m = t >> 1, half = t & 1;
            int row = m0 + m;
            bf16 tmp[16];
            if (row < N) {
                const float* sp = x + (size_t)row * DIN + kt + half * 16;
                float4 v0 = *(const float4*)(sp + 0);
                float4 v1 = *(const float4*)(sp + 4);
                float4 v2 = *(const float4*)(sp + 8);
                float4 v3 = *(const float4*)(sp + 12);
                tmp[0] = (bf16)v0.x; tmp[1] = (bf16)v0.y; tmp[2] = (bf16)v0.z; tmp[3] = (bf16)v0.w;
                tmp[4] = (bf16)v1.x; tmp[5] = (bf16)v1.y; tmp[6] = (bf16)v1.z; tmp[7] = (bf16)v1.w;
                tmp[8] = (bf16)v2.x; tmp[9] = (bf16)v2.y; tmp[10] = (bf16)v2.z; tmp[11] = (bf16)v2.w;
                tmp[12] = (bf16)v3.x; tmp[13] = (bf16)v3.y; tmp[14] = (bf16)v3.z; tmp[15] = (bf16)v3.w;
            } else {
#pragma unroll
                for (int i = 0; i < 16; i++) tmp[i] = (bf16)0.f;
            }
            *(uint4*)&Alds[m * 40 + half * 16] = *(uint4*)&tmp[0];
            *(uint4*)&Alds[m * 40 + half * 16 + 8] = *(uint4*)&tmp[8];
        }
#pragma unroll
        for (int i = 0; i < 2; i++) {
            int e = t + 256 * i;
            int c = e >> 2, seg = e & 3;
            const bf16* sp = Wt + (size_t)(colbase + c) * DIN + kt + seg * 8;
            *(uint4*)&Blds[c * 40 + seg * 8] = *(const uint4*)sp;
        }
        __syncthreads();

        bf16x8 af0 = *(bf16x8*)&Alds[(wv * 32 + l16) * 40 + k8];
        bf16x8 af1 = *(bf16x8*)&Alds[(wv * 32 + 16 + l16) * 40 + k8];
#pragma unroll
        for (int c = 0; c < 8; c++) {
            bf16x8 bfg = *(bf16x8*)&Blds[(c * 16 + l16) * 40 + k8];
            acc[0][c] = __builtin_amdgcn_mfma_f32_16x16x32_bf16(af0, bfg, acc[0][c], 0, 0, 0);
            acc[1][c] = __builtin_amdgcn_mfma_f32_16x16x32_bf16(af1, bfg, acc[1][c], 0, 0, 0);
        }
        __syncthreads();
    }

    // ---- epilogue: fused logits (fp32 acc) + swizzled bf16 store ----
    int h0 = colbase >> 6;
    float as8[8], ad8[8];
#pragma unroll
    for (int c = 0; c < 8; c++) {
        as8[c] = a_src[colbase + c * 16 + l16];
        ad8[c] = a_dst[colbase + c * 16 + l16];
    }
#pragma unroll
    for (int s = 0; s < 2; s++) {
        float ls[2][4] = {}, ldd[2][4] = {};
#pragma unroll
        for (int c = 0; c < 8; c++)
#pragma unroll
            for (int r = 0; r < 4; r++) {
                float v = acc[s][c][r];
                ls[c >> 2][r] += v * as8[c];
                ldd[c >> 2][r] += v * ad8[c];
            }
#pragma unroll
        for (int d = 1; d < 16; d <<= 1)
#pragma unroll
            for (int hh = 0; hh < 2; hh++)
#pragma unroll
                for (int r = 0; r < 4; r++) {
                    ls[hh][r] += __shfl_xor(ls[hh][r], d);
                    ldd[hh][r] += __shfl_xor(ldd[hh][r], d);
                }
        if (l16 == 0) {
#pragma unroll
            for (int hh = 0; hh < 2; hh++)
#pragma unroll
                for (int r = 0; r < 4; r++) {
                    int row = m0 + wv * 32 + s * 16 + quad * 4 + r;
                    if (row < N) {
                        als[row * HEADS + h0 + hh] = ls[hh][r];
                        ald[row * HEADS + h0 + hh] = ldd[hh][r];
                    }
                }
        }
        // swizzled store: one uint4 per (s,r)
#pragma unroll
        for (int r = 0; r < 4; r++) {
            int row = m0 + wv * 32 + s * 16 + quad * 4 + r;
            if (row < N) {
                bf16 t8[8];
#pragma unroll
                for (int c = 0; c < 8; c++) t8[c] = (bf16)acc[s][c][r];
                *(uint4*)&xpb[(size_t)row * HC + colbase + l16 * 8] = *(uint4*)t8;
            }
        }
    }
}

// ---------------------------------------------------------------------------
// CSR build — proven r0/r2 parallel chain
// ---------------------------------------------------------------------------
__global__ void deg_kernel(const int* __restrict__ dst, int* __restrict__ deg, int E) {
    int i = blockIdx.x * blockDim.x + threadIdx.x;
    if (i < E) atomicAdd(&deg[dst[i]], 1);
}

__global__ __launch_bounds__(256) void scan_sums(const int* __restrict__ deg,
                                                 int* __restrict__ bsum, int N) {
    int i = blockIdx.x * 256 + threadIdx.x;
    int v = (i < N) ? deg[i] : 0;
#pragma unroll
    for (int d = 32; d > 0; d >>= 1) v += __shfl_xor(v, d);
    __shared__ int p[4];
    if ((threadIdx.x & 63) == 0) p[threadIdx.x >> 6] = v;
    __syncthreads();
    if (threadIdx.x == 0) bsum[blockIdx.x] = p[0] + p[1] + p[2] + p[3];
}

__global__ __launch_bounds__(256) void scan_boffs(const int* __restrict__ bsum,
                                                  int* __restrict__ boffs, int NB) {
    int t = threadIdx.x, wid = t >> 6, lane = t & 63;
    int orig = (t < NB) ? bsum[t] : 0;
    int v = orig;
#pragma unroll
    for (int d = 1; d < 64; d <<= 1) {
        int y = __shfl_up(v, d);
        if (lane >= d) v += y;
    }
    __shared__ int wt[4];
    if (lane == 63) wt[wid] = v;
    __syncthreads();
    int add = 0;
#pragma unroll
    for (int ww = 0; ww < 4; ww++)
        if (ww < wid) add += wt[ww];
    v += add;
    if (t < NB) boffs[t] = v - orig;
}

__global__ __launch_bounds__(256) void scan_offs(const int* __restrict__ deg,
                                                 const int* __restrict__ boffs,
                                                 int* __restrict__ offs, int N) {
    int bI = blockIdx.x, t = threadIdx.x, wid = t >> 6, lane = t & 63;
    int i = bI * 256 + t;
    int orig = (i < N) ? deg[i] : 0;
    int v = orig;
#pragma unroll
    for (int d = 1; d < 64; d <<= 1) {
        int y = __shfl_up(v, d);
        if (lane >= d) v += y;
    }
    __shared__ int wt[4];
    if (lane == 63) wt[wid] = v;
    __syncthreads();
    int add = 0;
#pragma unroll
    for (int ww = 0; ww < 4; ww++)
        if (ww < wid) add += wt[ww];
    int incl = v + add;
    int base = boffs[bI];
    if (i < N) offs[i] = base + incl - orig;
    if (i == N - 1) offs[N] = base + incl;
}

__global__ void fill_kernel(const int* __restrict__ src, const int* __restrict__ dst,
                            const int* __restrict__ offs, int* __restrict__ deg,
                            int* __restrict__ csr, int E) {
    int i = blockIdx.x * blockDim.x + threadIdx.x;
    if (i < E) {
        int d = dst[i];
        int pos = offs[d] + atomicSub(&deg[d], 1) - 1;
        csr[pos] = src[i];
    }
}

// ---------------------------------------------------------------------------
// Aggregation: PERSISTENT WAVES + dynamic node claiming. Per-node body is the
// PROVEN 4-deep unguarded loop (byte-identical to r8's 94us kernel). Node
// acquisition: each wave atomicAdds one of 8 cacheline-padded partition
// counters (partition = blockIdx&7, ~6250 claims/counter => no contention).
// Removes the ~24% finished-but-held wave waste of static 4-wave workgroups.
// ---------------------------------------------------------------------------
#define AGG_BLOCKS 2048
__global__ __launch_bounds__(256) void agg_kernel(const bf16* __restrict__ xp,
                                                  const float* __restrict__ als,
                                                  const float* __restrict__ ald,
                                                  const int* __restrict__ offs,
                                                  const int* __restrict__ csr,
                                                  const float* __restrict__ bias,
                                                  float* __restrict__ out,
                                                  int* __restrict__ cnt, int N) {
    int lane = threadIdx.x & 63;
    int hp = lane >> 4, l16 = lane & 15;
    int part = blockIdx.x & 7;
    int psz = (N + 7) / 8;
    int pbase = part * psz;
    int pend = min(N, pbase + psz);

    for (;;) {
        int n = 0;
        if (lane == 0) n = pbase + atomicAdd(&cnt[part * 32], 1);
        n = __shfl(n, 0);
        if (n >= pend) break;

        float2 aldn = *(const float2*)&ald[n * HEADS + hp * 2];
        float2 alsn = *(const float2*)&als[n * HEADS + hp * 2];
        float es0 = lrelu(alsn.x + aldn.x);
        float es1 = lrelu(alsn.y + aldn.y);

        int start = offs[n];
        int deg = offs[n + 1] - start;

        float acc[8];
        {
            uint4 u = *(const uint4*)&xp[(size_t)n * HC + lane * 8];
            acc[0] = bflo(u.x); acc[1] = bfhi(u.x);
            acc[2] = bflo(u.y); acc[3] = bfhi(u.y);
            acc[4] = bflo(u.z); acc[5] = bfhi(u.z);
            acc[6] = bflo(u.w); acc[7] = bfhi(u.w);
        }
        float d0 = 1.f, d1 = 1.f;

        for (int c0 = 0; c0 < deg; c0 += 64) {
            int cnt2 = min(64, deg - c0);
            int sreg = (lane < cnt2) ? csr[start + c0 + lane] : 0;
            int jj = 0;
            for (; jj + 4 <= cnt2; jj += 4) {
                int s0 = __shfl(sreg, jj), s1 = __shfl(sreg, jj + 1);
                int s2 = __shfl(sreg, jj + 2), s3 = __shfl(sreg, jj + 3);
                float2 a0 = *(const float2*)&als[s0 * HEADS + hp * 2];
                float2 a1 = *(const float2*)&als[s1 * HEADS + hp * 2];
                float2 a2 = *(const float2*)&als[s2 * HEADS + hp * 2];
                float2 a3 = *(const float2*)&als[s3 * HEADS + hp * 2];
                uint4 u0 = *(const uint4*)&xp[(size_t)s0 * HC + lane * 8];
                uint4 u1 = *(const uint4*)&xp[(size_t)s1 * HC + lane * 8];
                uint4 u2 = *(const uint4*)&xp[(size_t)s2 * HC + lane * 8];
                uint4 u3 = *(const uint4*)&xp[(size_t)s3 * HC + lane * 8];
                float w00 = __expf(lrelu(a0.x + aldn.x) - es0), w01 = __expf(lrelu(a0.y + aldn.y) - es1);
                float w10 = __expf(lrelu(a1.x + aldn.x) - es0), w11 = __expf(lrelu(a1.y + aldn.y) - es1);
                float w20 = __expf(lrelu(a2.x + aldn.x) - es0), w21 = __expf(lrelu(a2.y + aldn.y) - es1);
                float w30 = __expf(lrelu(a3.x + aldn.x) - es0), w31 = __expf(lrelu(a3.y + aldn.y) - es1);
                fma8x2(acc, u0, w00, w01); d0 += w00; d1 += w01;
                fma8x2(acc, u1, w10, w11); d0 += w10; d1 += w11;
                fma8x2(acc, u2, w20, w21); d0 += w20; d1 += w21;
                fma8x2(acc, u3, w30, w31); d0 += w30; d1 += w31;
            }
            for (; jj < cnt2; jj++) {
                int s0 = __shfl(sreg, jj);
                float2 a0 = *(const float2*)&als[s0 * HEADS + hp * 2];
                uint4 u0 = *(const uint4*)&xp[(size_t)s0 * HC + lane * 8];
                float w00 = __expf(lrelu(a0.x + aldn.x) - es0), w01 = __expf(lrelu(a0.y + aldn.y) - es1);
                fma8x2(acc, u0, w00, w01); d0 += w00; d1 += w01;
            }
        }

        float i0 = 1.f / d0, i1 = 1.f / d1;
        size_t ob0 = (size_t)(hp * 2) * N * DOUT + (size_t)n * DOUT + l16;
        size_t ob1 = ob0 + (size_t)N * DOUT;
        int bb0 = (hp * 2) * DOUT + l16, bb1 = bb0 + DOUT;
#pragma unroll
        for (int c = 0; c < 4; c++) {
            __builtin_nontemporal_store(acc[c] * i0 + bias[bb0 + c * 16], &out[ob0 + c * 16]);
            __builtin_nontemporal_store(acc[c + 4] * i1 + bias[bb1 + c * 16], &out[ob1 + c * 16]);
        }
    }
}

// ---------------------------------------------------------------------------
extern "C" void kernel_launch(void* const* d_in, const int* in_sizes, int n_in,
                              void* d_out, int out_size, void* d_ws, size_t ws_size,
                              hipStream_t stream) {
    const float* x = (const float*)d_in[0];
    const int* ei = (const int*)d_in[1];
    const float* W = (const float*)d_in[2];
    const float* a_src = (const float*)d_in[3];
    const float* a_dst = (const float*)d_in[4];
    const float* b = (const float*)d_in[5];
    float* out = (float*)d_out;

    int N = in_sizes[0] / DIN;   // 50000
    int E = in_sizes[1] / 2;     // 500000
    const int* src = ei;
    const int* dst = ei + E;
    int NB = (N + 255) / 256;    // 196

    // workspace layout (~57 MB)
    bf16* xpb = (bf16*)d_ws;                          // N*512 bf16 (swizzled)
    float* als = (float*)(xpb + (size_t)N * HC);      // N*8
    float* ald = als + (size_t)N * HEADS;             // N*8
    bf16* Wt = (bf16*)(ald + (size_t)N * HEADS);      // 131072 bf16
    int* deg = (int*)(Wt + HEADS * DIN * DOUT);       // N
    int* offs = deg + N;                              // N+1
    int* bsum = offs + N + 1;                         // NB (<=256)
    int* boffs = bsum + 256;                          // NB
    int* csr = boffs + 256;                           // E
    int* cnt = csr + E;                               // 256 (8 padded counters)

    (void)hipMemsetAsync(deg, 0, (size_t)N * sizeof(int), stream);

    wprep_kernel<<<(HEADS * DIN * DOUT) / 256, 256, 0, stream>>>(W, Wt, cnt);
    dim3 ggrid((N + 127) / 128, HEADS / 2);
    gemm_kernel<<<ggrid, 256, 0, stream>>>(x, Wt, xpb, a_src, a_dst, als, ald, N);
    deg_kernel<<<(E + 255) / 256, 256, 0, stream>>>(dst, deg, E);
    scan_sums<<<NB, 256, 0, stream>>>(deg, bsum, N);
    scan_boffs<<<1, 256, 0, stream>>>(bsum, boffs, NB);
    scan_offs<<<NB, 256, 0, stream>>>(deg, boffs, offs, N);
    fill_kernel<<<(E + 255) / 256, 256, 0, stream>>>(src, dst, offs, deg, csr, E);
    agg_kernel<<<AGG_BLOCKS, 256, 0, stream>>>(xpb, als, ald, offs, csr, b, out, cnt, N);
}

// Round 10
// 339.169 us; speedup vs baseline: 1.1860x; 1.1860x over previous
//
#include <hip/hip_runtime.h>
#include <math.h>

#define HEADS 8
#define DOUT 64
#define DIN 256
#define HC 512  /* HEADS*DOUT */
#define NEG_SLOPE 0.2f

typedef __bf16 bf16;
typedef __bf16 bf16x8 __attribute__((ext_vector_type(8)));
typedef float f32x4 __attribute__((ext_vector_type(4)));

__device__ __forceinline__ float lrelu(float v) { return v > 0.f ? v : NEG_SLOPE * v; }
__device__ __forceinline__ float bflo(unsigned u) { return __uint_as_float(u << 16); }
__device__ __forceinline__ float bfhi(unsigned u) { return __uint_as_float(u & 0xffff0000u); }

// acc[0..3] weighted by w0 (head 2hp), acc[4..7] by w1 (head 2hp+1)
__device__ __forceinline__ void fma8x2(float* acc, uint4 u, float w0, float w1) {
    acc[0] += w0 * bflo(u.x); acc[1] += w0 * bfhi(u.x);
    acc[2] += w0 * bflo(u.y); acc[3] += w0 * bfhi(u.y);
    acc[4] += w1 * bflo(u.z); acc[5] += w1 * bfhi(u.z);
    acc[6] += w1 * bflo(u.w); acc[7] += w1 * bfhi(u.w);
}

// ---------------------------------------------------------------------------
// W prep: Wt[h][c][k] = bf16(W[h][k][c])
// ---------------------------------------------------------------------------
__global__ void wprep_kernel(const float* __restrict__ W, bf16* __restrict__ Wt) {
    int idx = blockIdx.x * 256 + threadIdx.x;
    int h = idx >> 14, rem = idx & 16383, k = rem >> 6, c = rem & 63;
    Wt[(((size_t)h * 64 + c) << 8) + k] = (bf16)W[idx];
}

// ---------------------------------------------------------------------------
// MFMA GEMM + fused logits — round-0 proven kernel (fp32 x staging,
// 128x128 tile, stride-40 LDS). xpb stored SWIZZLED:
//   elem index = row*512 + hp*128 + l16*8 + c,  actual col = hp*128 + c*16 + l16
// ---------------------------------------------------------------------------
__global__ __launch_bounds__(256) void gemm_kernel(const float* __restrict__ x,
                                                   const bf16* __restrict__ Wt,
                                                   bf16* __restrict__ xpb,
                                                   const float* __restrict__ a_src,
                                                   const float* __restrict__ a_dst,
                                                   float* __restrict__ als,
                                                   float* __restrict__ ald, int N) {
    __shared__ bf16 Alds[128 * 40];
    __shared__ bf16 Blds[128 * 40];

    int m0 = blockIdx.x * 128;
    int colbase = blockIdx.y * 128;  // heads 2y, 2y+1

    int t = threadIdx.x;
    int wv = t >> 6, lane = t & 63, quad = lane >> 4, l16 = lane & 15;
    int k8 = quad * 8;

    f32x4 acc[2][8] = {};

    for (int kt = 0; kt < DIN; kt += 32) {
        {
            int m = t >> 1, half = t & 1;
            int row = m0 + m;
            bf16 tmp[16];
            if (row < N) {
                const float* sp = x + (size_t)row * DIN + kt + half * 16;
                float4 v0 = *(const float4*)(sp + 0);
                float4 v1 = *(const float4*)(sp + 4);
                float4 v2 = *(const float4*)(sp + 8);
                float4 v3 = *(const float4*)(sp + 12);
                tmp[0] = (bf16)v0.x; tmp[1] = (bf16)v0.y; tmp[2] = (bf16)v0.z; tmp[3] = (bf16)v0.w;
                tmp[4] = (bf16)v1.x; tmp[5] = (bf16)v1.y; tmp[6] = (bf16)v1.z; tmp[7] = (bf16)v1.w;
                tmp[8] = (bf16)v2.x; tmp[9] = (bf16)v2.y; tmp[10] = (bf16)v2.z; tmp[11] = (bf16)v2.w;
                tmp[12] = (bf16)v3.x; tmp[13] = (bf16)v3.y; tmp[14] = (bf16)v3.z; tmp[15] = (bf16)v3.w;
            } else {
#pragma unroll
                for (int i = 0; i < 16; i++) tmp[i] = (bf16)0.f;
            }
            *(uint4*)&Alds[m * 40 + half * 16] = *(uint4*)&tmp[0];
            *(uint4*)&Alds[m * 40 + half * 16 + 8] = *(uint4*)&tmp[8];
        }
#pragma unroll
        for (int i = 0; i < 2; i++) {
            int e = t + 256 * i;
            int c = e >> 2, seg = e & 3;
            const bf16* sp = Wt + (size_t)(colbase + c) * DIN + kt + seg * 8;
            *(uint4*)&Blds[c * 40 + seg * 8] = *(const uint4*)sp;
        }
        __syncthreads();

        bf16x8 af0 = *(bf16x8*)&Alds[(wv * 32 + l16) * 40 + k8];
        bf16x8 af1 = *(bf16x8*)&Alds[(wv * 32 + 16 + l16) * 40 + k8];
#pragma unroll
        for (int c = 0; c < 8; c++) {
            bf16x8 bfg = *(bf16x8*)&Blds[(c * 16 + l16) * 40 + k8];
            acc[0][c] = __builtin_amdgcn_mfma_f32_16x16x32_bf16(af0, bfg, acc[0][c], 0, 0, 0);
            acc[1][c] = __builtin_amdgcn_mfma_f32_16x16x32_bf16(af1, bfg, acc[1][c], 0, 0, 0);
        }
        __syncthreads();
    }

    // ---- epilogue: fused logits (fp32 acc) + swizzled bf16 store ----
    int h0 = colbase >> 6;
    float as8[8], ad8[8];
#pragma unroll
    for (int c = 0; c < 8; c++) {
        as8[c] = a_src[colbase + c * 16 + l16];
        ad8[c] = a_dst[colbase + c * 16 + l16];
    }
#pragma unroll
    for (int s = 0; s < 2; s++) {
        float ls[2][4] = {}, ldd[2][4] = {};
#pragma unroll
        for (int c = 0; c < 8; c++)
#pragma unroll
            for (int r = 0; r < 4; r++) {
                float v = acc[s][c][r];
                ls[c >> 2][r] += v * as8[c];
                ldd[c >> 2][r] += v * ad8[c];
            }
#pragma unroll
        for (int d = 1; d < 16; d <<= 1)
#pragma unroll
            for (int hh = 0; hh < 2; hh++)
#pragma unroll
                for (int r = 0; r < 4; r++) {
                    ls[hh][r] += __shfl_xor(ls[hh][r], d);
                    ldd[hh][r] += __shfl_xor(ldd[hh][r], d);
                }
        if (l16 == 0) {
#pragma unroll
            for (int hh = 0; hh < 2; hh++)
#pragma unroll
                for (int r = 0; r < 4; r++) {
                    int row = m0 + wv * 32 + s * 16 + quad * 4 + r;
                    if (row < N) {
                        als[row * HEADS + h0 + hh] = ls[hh][r];
                        ald[row * HEADS + h0 + hh] = ldd[hh][r];
                    }
                }
        }
        // swizzled store: one uint4 per (s,r)
#pragma unroll
        for (int r = 0; r < 4; r++) {
            int row = m0 + wv * 32 + s * 16 + quad * 4 + r;
            if (row < N) {
                bf16 t8[8];
#pragma unroll
                for (int c = 0; c < 8; c++) t8[c] = (bf16)acc[s][c][r];
                *(uint4*)&xpb[(size_t)row * HC + colbase + l16 * 8] = *(uint4*)t8;
            }
        }
    }
}

// ---------------------------------------------------------------------------
// CSR build — proven r0/r2 parallel chain
// ---------------------------------------------------------------------------
__global__ void deg_kernel(const int* __restrict__ dst, int* __restrict__ deg, int E) {
    int i = blockIdx.x * blockDim.x + threadIdx.x;
    if (i < E) atomicAdd(&deg[dst[i]], 1);
}

__global__ __launch_bounds__(256) void scan_sums(const int* __restrict__ deg,
                                                 int* __restrict__ bsum, int N) {
    int i = blockIdx.x * 256 + threadIdx.x;
    int v = (i < N) ? deg[i] : 0;
#pragma unroll
    for (int d = 32; d > 0; d >>= 1) v += __shfl_xor(v, d);
    __shared__ int p[4];
    if ((threadIdx.x & 63) == 0) p[threadIdx.x >> 6] = v;
    __syncthreads();
    if (threadIdx.x == 0) bsum[blockIdx.x] = p[0] + p[1] + p[2] + p[3];
}

__global__ __launch_bounds__(256) void scan_boffs(const int* __restrict__ bsum,
                                                  int* __restrict__ boffs, int NB) {
    int t = threadIdx.x, wid = t >> 6, lane = t & 63;
    int orig = (t < NB) ? bsum[t] : 0;
    int v = orig;
#pragma unroll
    for (int d = 1; d < 64; d <<= 1) {
        int y = __shfl_up(v, d);
        if (lane >= d) v += y;
    }
    __shared__ int wt[4];
    if (lane == 63) wt[wid] = v;
    __syncthreads();
    int add = 0;
#pragma unroll
    for (int ww = 0; ww < 4; ww++)
        if (ww < wid) add += wt[ww];
    v += add;
    if (t < NB) boffs[t] = v - orig;
}

__global__ __launch_bounds__(256) void scan_offs(const int* __restrict__ deg,
                                                 const int* __restrict__ boffs,
                                                 int* __restrict__ offs, int N) {
    int bI = blockIdx.x, t = threadIdx.x, wid = t >> 6, lane = t & 63;
    int i = bI * 256 + t;
    int orig = (i < N) ? deg[i] : 0;
    int v = orig;
#pragma unroll
    for (int d = 1; d < 64; d <<= 1) {
        int y = __shfl_up(v, d);
        if (lane >= d) v += y;
    }
    __shared__ int wt[4];
    if (lane == 63) wt[wid] = v;
    __syncthreads();
    int add = 0;
#pragma unroll
    for (int ww = 0; ww < 4; ww++)
        if (ww < wid) add += wt[ww];
    int incl = v + add;
    int base = boffs[bI];
    if (i < N) offs[i] = base + incl - orig;
    if (i == N - 1) offs[N] = base + incl;
}

__global__ void fill_kernel(const int* __restrict__ src, const int* __restrict__ dst,
                            const int* __restrict__ offs, int* __restrict__ deg,
                            int* __restrict__ csr, int E) {
    int i = blockIdx.x * blockDim.x + threadIdx.x;
    if (i < E) {
        int d = dst[i];
        int pos = offs[d] + atomicSub(&deg[d], 1) - 1;
        csr[pos] = src[i];
    }
}

// ---------------------------------------------------------------------------
// Aggregation: ONE WAVE PER DST NODE, all 8 heads. Lane j: hp=j>>4, l16=j&15.
// PROVEN 4-deep unguarded loop + serial tail; nontemporal out stores (best
// measured agg: 93.9-94.2us, r8). Structure ledger: guarded-8 (r1, 128us),
// masked-8 (r5, 100us), persistent+atomic-claim (r9, 154us) all regressed;
// FETCH invariant at 284MB => random-gather fabric floor. FROZEN.
// ---------------------------------------------------------------------------
__global__ __launch_bounds__(256) void agg_kernel(const bf16* __restrict__ xp,
                                                  const float* __restrict__ als,
                                                  const float* __restrict__ ald,
                                                  const int* __restrict__ offs,
                                                  const int* __restrict__ csr,
                                                  const float* __restrict__ bias,
                                                  float* __restrict__ out, int N) {
    int n = blockIdx.x * 4 + (threadIdx.x >> 6);
    if (n >= N) return;
    int lane = threadIdx.x & 63;
    int hp = lane >> 4, l16 = lane & 15;

    float2 aldn = *(const float2*)&ald[n * HEADS + hp * 2];
    float2 alsn = *(const float2*)&als[n * HEADS + hp * 2];
    float es0 = lrelu(alsn.x + aldn.x);
    float es1 = lrelu(alsn.y + aldn.y);

    int start = offs[n];
    int deg = offs[n + 1] - start;

    float acc[8];
    {
        uint4 u = *(const uint4*)&xp[(size_t)n * HC + lane * 8];
        acc[0] = bflo(u.x); acc[1] = bfhi(u.x);
        acc[2] = bflo(u.y); acc[3] = bfhi(u.y);
        acc[4] = bflo(u.z); acc[5] = bfhi(u.z);
        acc[6] = bflo(u.w); acc[7] = bfhi(u.w);
    }
    float d0 = 1.f, d1 = 1.f;

    for (int c0 = 0; c0 < deg; c0 += 64) {
        int cnt = min(64, deg - c0);
        int sreg = (lane < cnt) ? csr[start + c0 + lane] : 0;
        int jj = 0;
        for (; jj + 4 <= cnt; jj += 4) {
            int s0 = __shfl(sreg, jj), s1 = __shfl(sreg, jj + 1);
            int s2 = __shfl(sreg, jj + 2), s3 = __shfl(sreg, jj + 3);
            float2 a0 = *(const float2*)&als[s0 * HEADS + hp * 2];
            float2 a1 = *(const float2*)&als[s1 * HEADS + hp * 2];
            float2 a2 = *(const float2*)&als[s2 * HEADS + hp * 2];
            float2 a3 = *(const float2*)&als[s3 * HEADS + hp * 2];
            uint4 u0 = *(const uint4*)&xp[(size_t)s0 * HC + lane * 8];
            uint4 u1 = *(const uint4*)&xp[(size_t)s1 * HC + lane * 8];
            uint4 u2 = *(const uint4*)&xp[(size_t)s2 * HC + lane * 8];
            uint4 u3 = *(const uint4*)&xp[(size_t)s3 * HC + lane * 8];
            float w00 = __expf(lrelu(a0.x + aldn.x) - es0), w01 = __expf(lrelu(a0.y + aldn.y) - es1);
            float w10 = __expf(lrelu(a1.x + aldn.x) - es0), w11 = __expf(lrelu(a1.y + aldn.y) - es1);
            float w20 = __expf(lrelu(a2.x + aldn.x) - es0), w21 = __expf(lrelu(a2.y + aldn.y) - es1);
            float w30 = __expf(lrelu(a3.x + aldn.x) - es0), w31 = __expf(lrelu(a3.y + aldn.y) - es1);
            fma8x2(acc, u0, w00, w01); d0 += w00; d1 += w01;
            fma8x2(acc, u1, w10, w11); d0 += w10; d1 += w11;
            fma8x2(acc, u2, w20, w21); d0 += w20; d1 += w21;
            fma8x2(acc, u3, w30, w31); d0 += w30; d1 += w31;
        }
        for (; jj < cnt; jj++) {
            int s0 = __shfl(sreg, jj);
            float2 a0 = *(const float2*)&als[s0 * HEADS + hp * 2];
            uint4 u0 = *(const uint4*)&xp[(size_t)s0 * HC + lane * 8];
            float w00 = __expf(lrelu(a0.x + aldn.x) - es0), w01 = __expf(lrelu(a0.y + aldn.y) - es1);
            fma8x2(acc, u0, w00, w01); d0 += w00; d1 += w01;
        }
    }

    float i0 = 1.f / d0, i1 = 1.f / d1;
    size_t ob0 = (size_t)(hp * 2) * N * DOUT + (size_t)n * DOUT + l16;
    size_t ob1 = ob0 + (size_t)N * DOUT;
    int bb0 = (hp * 2) * DOUT + l16, bb1 = bb0 + DOUT;
#pragma unroll
    for (int c = 0; c < 4; c++) {
        __builtin_nontemporal_store(acc[c] * i0 + bias[bb0 + c * 16], &out[ob0 + c * 16]);
        __builtin_nontemporal_store(acc[c + 4] * i1 + bias[bb1 + c * 16], &out[ob1 + c * 16]);
    }
}

// ---------------------------------------------------------------------------
extern "C" void kernel_launch(void* const* d_in, const int* in_sizes, int n_in,
                              void* d_out, int out_size, void* d_ws, size_t ws_size,
                              hipStream_t stream) {
    const float* x = (const float*)d_in[0];
    const int* ei = (const int*)d_in[1];
    const float* W = (const float*)d_in[2];
    const float* a_src = (const float*)d_in[3];
    const float* a_dst = (const float*)d_in[4];
    const float* b = (const float*)d_in[5];
    float* out = (float*)d_out;

    int N = in_sizes[0] / DIN;   // 50000
    int E = in_sizes[1] / 2;     // 500000
    const int* src = ei;
    const int* dst = ei + E;
    int NB = (N + 255) / 256;    // 196

    // workspace layout (~57 MB)
    bf16* xpb = (bf16*)d_ws;                          // N*512 bf16 (swizzled)
    float* als = (float*)(xpb + (size_t)N * HC);      // N*8
    float* ald = als + (size_t)N * HEADS;             // N*8
    bf16* Wt = (bf16*)(ald + (size_t)N * HEADS);      // 131072 bf16
    int* deg = (int*)(Wt + HEADS * DIN * DOUT);       // N
    int* offs = deg + N;                              // N+1
    int* bsum = offs + N + 1;                         // NB (<=256)
    int* boffs = bsum + 256;                          // NB
    int* csr = boffs + 256;                           // E

    (void)hipMemsetAsync(deg, 0, (size_t)N * sizeof(int), stream);

    wprep_kernel<<<(HEADS * DIN * DOUT) / 256, 256, 0, stream>>>(W, Wt);
    dim3 ggrid((N + 127) / 128, HEADS / 2);
    gemm_kernel<<<ggrid, 256, 0, stream>>>(x, Wt, xpb, a_src, a_dst, als, ald, N);
    deg_kernel<<<(E + 255) / 256, 256, 0, stream>>>(dst, deg, E);
    scan_sums<<<NB, 256, 0, stream>>>(deg, bsum, N);
    scan_boffs<<<1, 256, 0, stream>>>(bsum, boffs, NB);
    scan_offs<<<NB, 256, 0, stream>>>(deg, boffs, offs, N);
    fill_kernel<<<(E + 255) / 256, 256, 0, stream>>>(src, dst, offs, deg, csr, E);
    agg_kernel<<<(N + 3) / 4, 256, 0, stream>>>(xpb, als, ald, offs, csr, b, out, N);
}